// Round 8
// baseline (117.214 us; speedup 1.0000x reference)
//
#include <hip/hip_runtime.h>
#include <hip/hip_bf16.h>
#include <stdint.h>

// fp32 in / fp32 out; bf16 MFMA internally (threshold 6.6e-2 >> bf16 quant err)
// Structure: triple-buffered LDS-DMA staging, 2 tiles ahead, counted-vmcnt
// barriers (T3/T4) — the memory pipe is never drained in the main loop.
#define M_ROWS (4*128*512)   // 262144 flattened (b,s,n) rows
#define FDIM 362
#define TROWS 16             // rows per tile (one 16x16x32 A-frag)
#define ROWB 1448            // bytes per fp32 row
#define TILEB (TROWS*ROWB)   // 23168 B per tile buffer
#define CPW 362              // 16B chunks per wave (4*362 = 1448 = TILEB/16)
#define GRID 1024
#define TPB 16               // 1024*16*16 = 262144 rows
#define OUT_HALF 16777216    // M_ROWS*64

typedef __attribute__((ext_vector_type(8))) short bf16x8;
typedef __attribute__((ext_vector_type(4))) float f32x4;

template<int N> struct Ic { static constexpr int value = N; };

__device__ __forceinline__ bf16x8 pack8(float2 a, float2 b, float2 c, float2 d) {
  union { __hip_bfloat162 h[4]; bf16x8 v; } t;
  t.h[0] = __float22bfloat162_rn(a);
  t.h[1] = __float22bfloat162_rn(b);
  t.h[2] = __float22bfloat162_rn(c);
  t.h[3] = __float22bfloat162_rn(d);
  return t.v;
}
__device__ __forceinline__ float2 ld2(const float* p) { return *(const float2*)p; }

__global__ __launch_bounds__(256, 2) void dfl_kernel(
    const float* __restrict__ x,
    const float* __restrict__ Wg,
    const float* __restrict__ Wgb,
    const float* __restrict__ Wh,
    const float* __restrict__ Whb,
    float* __restrict__ out)
{
  // triple-buffered fp32 A tiles (linear 23168B copies) + per-wave transpose buf
  __shared__ __attribute__((aligned(16))) unsigned char Ab[3][TILEB]; // 69504 B
  __shared__ __attribute__((aligned(16))) unsigned char tb[4*2048];   // 8 KiB

  const int tid  = threadIdx.x;
  const int lane = tid & 63;
  const int wv   = tid >> 6;       // 4 waves = 4 col-slabs: g0 g1 h0 h1
  const int q    = lane >> 4;
  const int l15  = lane & 15;
  const bool is_h = wv >= 2;
  const int colb  = (wv & 1) * 32;
  const float* Wsel  = is_h ? Wh  : Wg;
  const float* Wbsel = is_h ? Whb : Wgb;

  // ---- B-fragment preload (fp32 -> bf16 regs, once per block) ----
  bf16x8 bw[2][12];
  float biasf[2], w0f[2];
#pragma unroll
  for (int f = 0; f < 2; ++f) {
    const int dloc = colb + f*16 + l15;                 // 0..63
    const float* wrow = Wsel + (size_t)dloc * FDIM;
    biasf[f] = Wbsel[dloc];
    w0f[f]   = wrow[0];
#pragma unroll
    for (int k = 0; k < 12; ++k) {
      float2 t0 = make_float2(0.f,0.f), t1 = t0, t2 = t0, t3 = t0;
      if (k < 11) {
        const float* p = wrow + k*32 + q*8;
        t0 = ld2(p); t1 = ld2(p+2); t2 = ld2(p+4); t3 = ld2(p+6);
      } else if (q == 0) {
        t0 = ld2(wrow+352); t1 = ld2(wrow+354); t2 = ld2(wrow+356); t3 = ld2(wrow+358);
      } else if (q == 1) {
        t0 = ld2(wrow+360);                              // f=360,361; rest pad 0
      }
      bw[f][k] = pack8(t0, t1, t2, t3);                  // zeros at f>=362
    }
  }

  // ---- staging: async DMA, zero VGPR cost; EXACTLY 6 VMEM ops per wave ----
  auto stage = [&](int tile, int p) {
    const unsigned char* src = (const unsigned char*)(x + (size_t)tile * TROWS * FDIM);
    unsigned char* dst = &Ab[p][0];
#pragma unroll
    for (int j = 0; j < 6; ++j) {
      const int cbase = wv*CPW + j*64;                   // wave-uniform
      if (lane < CPW - j*64) {                           // j<5: all lanes; j=5: 42
        __builtin_amdgcn_global_load_lds(
            (const __attribute__((address_space(1))) unsigned int*)(src + (size_t)(cbase + lane)*16),
            (__attribute__((address_space(3))) unsigned int*)(dst + cbase*16),
            16, 0, 0);                                   // HW adds lane*16 to dest
      }
    }
  };

  unsigned char* wb = tb + wv*2048;
  float* outp = out + (is_h ? OUT_HALF : 0) + colb;

  // One round. VMEM order per wave is pinned by sched_barrier(0) fences:
  //   P(1 partner load) ; S(6 DMAs, optional) ; compute ; E(2 stores) ; wait
  // Steady-state wait: ops newer than stage(i+1)'s last DMA =
  //   E_{i-1}(2) + P_i(1) + S_i(6) + E_i(2) = 11  -> s_waitcnt vmcnt(11)
  auto round = [&](int i, auto sflag, auto wc) {
    const int p  = i % 3;
    const int m0 = ((int)blockIdx.x + i*GRID) * TROWS;

    // partner feature-0 (issued BEFORE stage so its use-wait is vmcnt(6), not 0)
    const float rp = x[(size_t)((m0 ^ 512) + l15) * FDIM];  // all lanes: 1 VMEM
    __builtin_amdgcn_sched_barrier(0);
    if constexpr (decltype(sflag)::value)
      stage((int)blockIdx.x + (i+2)*GRID, (i+2) % 3);
    __builtin_amdgcn_sched_barrier(0);

    const unsigned char* AbP = &Ab[p][0];
    const unsigned char* ap  = AbP + l15*ROWB + q*32;
    f32x4 acc0 = {biasf[0],biasf[0],biasf[0],biasf[0]};
    f32x4 acc1 = {biasf[1],biasf[1],biasf[1],biasf[1]};
#pragma unroll
    for (int k = 0; k < 11; ++k) {
      const unsigned char* pk = ap + k*128;              // 8B-aligned ds_read_b64
      bf16x8 av = pack8(*(const float2*)pk, *(const float2*)(pk+8),
                        *(const float2*)(pk+16), *(const float2*)(pk+24));
      acc0 = __builtin_amdgcn_mfma_f32_16x16x32_bf16(av, bw[0][k], acc0, 0,0,0);
      acc1 = __builtin_amdgcn_mfma_f32_16x16x32_bf16(av, bw[1][k], acc1, 0,0,0);
    }
    { // k=11: only features 352..361 valid — masked reads, NO row overrun
      const unsigned char* pk = ap + 11*128;
      float2 z2 = make_float2(0.f,0.f), f0 = z2, f1 = z2, f2 = z2, f3 = z2;
      if (q == 0) {
        f0 = *(const float2*)pk;      f1 = *(const float2*)(pk+8);
        f2 = *(const float2*)(pk+16); f3 = *(const float2*)(pk+24);
      } else if (q == 1) {
        f0 = *(const float2*)pk;                          // features 360,361
      }
      bf16x8 av = pack8(f0, f1, f2, f3);
      acc0 = __builtin_amdgcn_mfma_f32_16x16x32_bf16(av, bw[0][11], acc0, 0,0,0);
      acc1 = __builtin_amdgcn_mfma_f32_16x16x32_bf16(av, bw[1][11], acc1, 0,0,0);
    }

    const float rs = *(const float*)(AbP + l15*ROWB);    // x[row][0] from LDS
    const float cval = is_h ? -(rs + rp)*0.5f : (rp - rs)*0.5f;

    // epilogue: correction fma, transpose via wave-private LDS, 2 stores
#pragma unroll
    for (int jj = 0; jj < 4; ++jj) {
      const float cc = __shfl(cval, q*4 + jj, 64);
      const int rl = q*4 + jj;
#pragma unroll
      for (int fn = 0; fn < 2; ++fn) {
        const float v = (fn ? acc1[jj] : acc0[jj]) + cc * w0f[fn];
        const int col = fn*16 + l15;
        const int boff = rl*128 + ((((col>>2) ^ (rl&7))) << 4) + ((col&3) << 2);
        *(float*)(wb + boff) = v;
      }
    }
#pragma unroll
    for (int s = 0; s < 2; ++s) {
      const int rr = s*8 + (lane >> 3);
      const int cs = lane & 7;
      f32x4 vv = *(const f32x4*)(wb + rr*128 + (((cs ^ (rr&7))) << 4));
      *(f32x4*)(outp + (size_t)(m0 + rr)*64 + cs*4) = vv;   // 2x dwordx4
    }

    __builtin_amdgcn_sched_barrier(0);
    if constexpr (decltype(wc)::value >= 0) {
      asm volatile("s_waitcnt vmcnt(%0)" :: "i"(decltype(wc)::value) : "memory");
      __builtin_amdgcn_s_barrier();                      // raw barrier: NO drain
    }
    __builtin_amdgcn_sched_barrier(0);
  };

  // ---- prologue: zero vmcnt baseline, then stage tiles 0 and 1 ----
  __builtin_amdgcn_sched_barrier(0);
  asm volatile("s_waitcnt vmcnt(0)" ::: "memory");       // W/bias loads drained
  stage((int)blockIdx.x, 0);
  stage((int)blockIdx.x + GRID, 1);
  __builtin_amdgcn_sched_barrier(0);
  asm volatile("s_waitcnt vmcnt(6)" ::: "memory");       // stage(0) done; (1) in flight
  __builtin_amdgcn_s_barrier();
  __builtin_amdgcn_sched_barrier(0);

  round(0, Ic<1>{}, Ic<9>{});                            // ensure stage(1)
  for (int i = 1; i <= 13; ++i) round(i, Ic<1>{}, Ic<11>{});  // steady state
  round(14, Ic<0>{}, Ic<5>{});                           // no stage; ensure stage(15)
  round(15, Ic<0>{}, Ic<-1>{});                          // final: no wait
}

extern "C" void kernel_launch(void* const* d_in, const int* in_sizes, int n_in,
                              void* d_out, int out_size, void* d_ws, size_t ws_size,
                              hipStream_t stream) {
  (void)in_sizes; (void)n_in; (void)d_ws; (void)ws_size; (void)out_size;
  const float* x   = (const float*)d_in[0];
  const float* Wg  = (const float*)d_in[1];
  const float* Wgb = (const float*)d_in[2];
  const float* Wh  = (const float*)d_in[3];
  const float* Whb = (const float*)d_in[4];
  float* out = (float*)d_out;
  dfl_kernel<<<GRID, 256, 0, stream>>>(x, Wg, Wgb, Wh, Whb, out);
}